// Round 5
// baseline (217.807 us; speedup 1.0000x reference)
//
#include <hip/hip_runtime.h>

// ---------------------------------------------------------------------------
// SE3 conv layer. CSR-built scatter (no f32 atomics) + f16-MFMA edge compute.
//   mix[e, lv] = sum_{ku} y[e,ku] * W2r[ku, lv],  y[e,k*16+u] = h[e,k]*x[e,u]
//   h = silu(radial @ W1/4);  W2r pre-packed (scaled 1/32) as f16 B-fragments.
// A-frag built with v_perm (h-half duplicate) + v_pk_mul_f16.
// ws: [ mix E*48 f32 | offs N+1 i32 | curs N i32 | eord E i32 | (align) Bfrag 96KB ]
// ---------------------------------------------------------------------------

typedef _Float16 f16x2 __attribute__((ext_vector_type(2)));
typedef _Float16 f16x8 __attribute__((ext_vector_type(8)));
typedef __fp16  g16x2 __attribute__((ext_vector_type(2)));   // cvt_pkrtz result type
typedef float f32x4 __attribute__((ext_vector_type(4)));

union AFrag { unsigned int u[4]; f16x2 h2[4]; f16x8 v; };
union BFrag { uint4 u4; f16x8 v; };
union HW { g16x2 g; f16x2 f; unsigned int u; };

// ---------------------------- CSR build ------------------------------------

__global__ __launch_bounds__(256)
void hist_kernel(const int* __restrict__ ei, int* __restrict__ counts, int E) {
    int e = blockIdx.x * blockDim.x + threadIdx.x;
    if (e < E) atomicAdd(&counts[ei[E + e] + 1], 1);
}

// chunk-serial scan: 1 block, each thread owns ceil(n/1024) contiguous elems.
__global__ __launch_bounds__(1024)
void scan_kernel(int* __restrict__ data, int n) {
    __shared__ int wsum[16];
    int tid = threadIdx.x, lane = tid & 63, wid = tid >> 6;
    int ch = (n + 1023) >> 10;
    int beg = tid * ch;
    int end = beg + ch; if (end > n) end = n;

    int s = 0;
    for (int i = beg; i < end; ++i) s += data[i];

    int v = s;
    #pragma unroll
    for (int off = 1; off < 64; off <<= 1) {
        int t = __shfl_up(v, off, 64);
        if (lane >= off) v += t;
    }
    if (lane == 63) wsum[wid] = v;
    __syncthreads();
    if (wid == 0 && lane < 16) {
        int w = wsum[lane];
        #pragma unroll
        for (int off = 1; off < 16; off <<= 1) {
            int t = __shfl_up(w, off, 16);
            if (lane >= off) w += t;
        }
        wsum[lane] = w;
    }
    __syncthreads();
    int run = (v - s) + (wid > 0 ? wsum[wid - 1] : 0);   // exclusive offset
    for (int i = beg; i < end; ++i) {
        run += data[i];
        data[i] = run;
    }
}

__global__ __launch_bounds__(256)
void scatter_kernel(const int* __restrict__ ei, const int* __restrict__ offs,
                    int* __restrict__ cursor, int* __restrict__ eord, int E) {
    int e = blockIdx.x * blockDim.x + threadIdx.x;
    if (e >= E) return;
    int dst = ei[E + e];
    int pos = offs[dst] + atomicAdd(&cursor[dst], 1);
    eord[pos] = e;
}

// ------------------------- B-fragment pre-pack (f16) -----------------------
// Bfrag[f][lane][j], f = ks*3+nt, ku = ks*32 + (lane>>4)*8 + j,
// k=ku>>4, u=ku&15, n = nt*16 + (lane&15), l=n>>4, v=n&15; val = W2/32.

__global__ __launch_bounds__(256)
void bfrag_prep_kernel(const float* __restrict__ W2, _Float16* __restrict__ bfrag) {
    int t = blockIdx.x * 256 + threadIdx.x;
    if (t >= 96 * 512) return;
    int f = t >> 9;
    int rr = t & 511;
    int lane = rr >> 3, j = rr & 7;
    int ks = f / 3, nt = f - 3 * ks;
    int q = lane >> 4, c = lane & 15;
    int ku = ks * 32 + q * 8 + j;
    int k = ku >> 4, u = ku & 15;
    int n = nt * 16 + c;
    int l = n >> 4, v = n & 15;
    float val = W2[(size_t)k * 768 + l * 256 + u * 16 + v] * 0.03125f;
    bfrag[t] = (_Float16)val;
}

// --------------------------- MFMA edge kernel ------------------------------
// block = 256 = 4 waves; wave owns 64 edges (4 M-tiles of 16).

__global__ __launch_bounds__(256)
void edge_mfma_kernel(const float* __restrict__ nf, const int* __restrict__ ei,
                      const float* __restrict__ radial, const float* __restrict__ W1,
                      const _Float16* __restrict__ bfrag,
                      float* __restrict__ mix, int E) {
    __shared__ unsigned int h_lds[4][64][32];   // f16 pairs (k=2t,2t+1), XOR-swizzled

    int tid = threadIdx.x;
    int wave = tid >> 6;
    int lane = tid & 63;
    int r_ = lane & 15;
    int q  = lane >> 4;
    int qh = q >> 1;                 // which half of the h-pair this lane needs
    int ul = (q & 1) * 8;            // u base for A-frag
    unsigned int sel = qh ? 0x03020302u : 0x01000100u;   // v_perm dup selector

    int ebase = blockIdx.x * 256 + wave * 64;

    // ---- phase 1: h[e][k], lane owns k = lane; store packed f16 pairs ----
    float w1c[16];
    #pragma unroll
    for (int u = 0; u < 16; ++u)
        w1c[u] = W1[u * 64 + lane] * 0.25f;      // fold 1/sqrt(16)

    #pragma unroll 2
    for (int el = 0; el < 64; ++el) {
        int e = ebase + el; if (e >= E) e = E - 1;       // wave-uniform clamp
        const float* rp = radial + (size_t)e * 16;
        float z = 0.f;
        #pragma unroll
        for (int u = 0; u < 16; ++u) z = fmaf(rp[u], w1c[u], z);
        float h = z * __builtin_amdgcn_rcpf(1.0f + __expf(-z));   // silu
        float hn = __shfl_xor(h, 1);
        if (!(lane & 1)) {
            HW w; w.g = __builtin_amdgcn_cvt_pkrtz(h, hn);   // (k=2t, k=2t+1)
            int t = lane >> 1;
            h_lds[wave][el][t ^ (el & 31)] = w.u;
        }
    }

    // ---- phase 2: x rows for the wave's 4 M-tiles, packed f16 ----
    HW xp[4][4];
    #pragma unroll
    for (int m = 0; m < 4; ++m) {
        int e = ebase + m * 16 + r_; if (e >= E) e = E - 1;
        int src = ei[e];
        const float* xpp = nf + (size_t)src * 16 + ul;
        float4 a = *(const float4*)xpp;
        float4 b = *(const float4*)(xpp + 4);
        xp[m][0].g = __builtin_amdgcn_cvt_pkrtz(a.x, a.y);
        xp[m][1].g = __builtin_amdgcn_cvt_pkrtz(a.z, a.w);
        xp[m][2].g = __builtin_amdgcn_cvt_pkrtz(b.x, b.y);
        xp[m][3].g = __builtin_amdgcn_cvt_pkrtz(b.z, b.w);
    }

    // ---- phase 3: K-loop, 32 steps of K=32 ----
    f32x4 acc[4][3];
    #pragma unroll
    for (int m = 0; m < 4; ++m)
        #pragma unroll
        for (int nt = 0; nt < 3; ++nt)
            acc[m][nt] = (f32x4){0.f, 0.f, 0.f, 0.f};

    for (int ks = 0; ks < 32; ++ks) {
        BFrag b[3];
        #pragma unroll
        for (int nt = 0; nt < 3; ++nt)
            b[nt].u4 = *(const uint4*)(bfrag + (size_t)(ks * 3 + nt) * 512 + lane * 8);
        #pragma unroll
        for (int m = 0; m < 4; ++m) {
            int el = m * 16 + r_;
            unsigned int hw = h_lds[wave][el][ks ^ (el & 31)];
            HW hv; hv.u = __builtin_amdgcn_perm(hw, hw, sel);  // dup needed half
            AFrag a;
            #pragma unroll
            for (int p2 = 0; p2 < 4; ++p2)
                a.h2[p2] = hv.f * xp[m][p2].f;                 // v_pk_mul_f16
            #pragma unroll
            for (int nt = 0; nt < 3; ++nt)
                acc[m][nt] = __builtin_amdgcn_mfma_f32_16x16x32_f16(a.v, b[nt].v, acc[m][nt], 0, 0, 0);
        }
    }

    // ---- epilogue: C layout col=lane&15, row=(lane>>4)*4+i ----
    #pragma unroll
    for (int m = 0; m < 4; ++m) {
        #pragma unroll
        for (int i = 0; i < 4; ++i) {
            int e = ebase + m * 16 + q * 4 + i;
            if (e < E) {
                float* mp = mix + (size_t)e * 48 + r_;
                mp[0]  = acc[m][0][i];
                mp[16] = acc[m][1][i];
                mp[32] = acc[m][2][i];
            }
        }
    }
}

// ------------------------------ gather -------------------------------------

__global__ __launch_bounds__(256)
void gather_kernel(const float* __restrict__ mix, const float* __restrict__ sh,
                   const int* __restrict__ eord, const int* __restrict__ offs,
                   const float* __restrict__ nf, const float* __restrict__ Wsi,
                   float* __restrict__ out, int N) {
    int node = blockIdx.x * 4 + (threadIdx.x >> 6);
    if (node >= N) return;
    int lane = threadIdx.x & 63;

    auto chmap = [](int c, int& mi, int& si) {
        if (c < 16)      { mi = c;                si = 0; }
        else if (c < 64) { int t = c - 16; mi = 16 + t / 3; si = 1 + t % 3; }
        else             { int t = c - 64; mi = 32 + t / 5; si = 4 + t % 5; }
    };
    int mi0, si0, mi1, si1, mi2 = 0, si2 = 0;
    chmap(lane, mi0, si0);
    chmap(lane + 64, mi1, si1);
    if (lane < 16) chmap(lane + 128, mi2, si2);

    float acc0 = 0.0f, acc1 = 0.0f, acc2 = 0.0f;
    int off = offs[node], end = offs[node + 1];
    for (int i = off; i < end; ++i) {
        int e = eord[i];
        const float* m = mix + (size_t)e * 48;
        const float* s = sh + (size_t)e * 9;
        acc0 = fmaf(m[mi0], s[si0], acc0);
        acc1 = fmaf(m[mi1], s[si1], acc1);
        if (lane < 16) acc2 = fmaf(m[mi2], s[si2], acc2);
    }

    if (lane < 16) {
        const float* xr = nf + (size_t)node * 16;
        float si = 0.0f;
        #pragma unroll
        for (int u = 0; u < 16; ++u)
            si = fmaf(xr[u], Wsi[u * 16 + lane], si);
        acc0 = fmaf(si, 0.25f, acc0);
    }

    float* orow = out + (size_t)node * 144;
    orow[lane] = acc0;
    orow[lane + 64] = acc1;
    if (lane < 16) orow[lane + 128] = acc2;
}

// ------------------------- fallback (atomic path) --------------------------

__global__ __launch_bounds__(256)
void si_init_kernel(const float* __restrict__ nf, const float* __restrict__ Wsi,
                    float* __restrict__ out, int N) {
    int t = blockIdx.x * blockDim.x + threadIdx.x;
    int total = N * 144;
    if (t >= total) return;
    int n = t / 144;
    int c = t - n * 144;
    float val = 0.0f;
    if (c < 16) {
        const float* xr = nf + n * 16;
        #pragma unroll
        for (int u = 0; u < 16; ++u)
            val = fmaf(xr[u], Wsi[u * 16 + c], val);
        val *= 0.25f;
    }
    out[t] = val;
}

__global__ __launch_bounds__(256)
void edge_kernel_atomic(const float* __restrict__ nf, const int* __restrict__ ei,
                        const float* __restrict__ sh, const float* __restrict__ radial,
                        const float* __restrict__ W1, const float* __restrict__ W2,
                        float* __restrict__ out, int E) {
    int e = blockIdx.x * blockDim.x + threadIdx.x;
    if (e >= E) return;
    int src = ei[e];
    int dst = ei[E + e];
    float r[16], x[16];
    #pragma unroll
    for (int u = 0; u < 16; ++u) r[u] = radial[e * 16 + u] * 0.25f;
    #pragma unroll
    for (int u = 0; u < 16; ++u) x[u] = nf[src * 16 + u] * 0.03125f;
    float acc[48];
    #pragma unroll
    for (int j = 0; j < 48; ++j) acc[j] = 0.0f;
    for (int k = 0; k < 64; ++k) {
        float z = 0.0f;
        #pragma unroll
        for (int u = 0; u < 16; ++u) z = fmaf(r[u], W1[u * 64 + k], z);
        float hk = z / (1.0f + __expf(-z));
        const float* w2k = W2 + k * 768;
        #pragma unroll 4
        for (int u = 0; u < 16; ++u) {
            float p = hk * x[u];
            const float* w = w2k + u * 16;
            #pragma unroll
            for (int l = 0; l < 3; ++l)
                #pragma unroll
                for (int v = 0; v < 16; ++v)
                    acc[l * 16 + v] = fmaf(p, w[l * 256 + v], acc[l * 16 + v]);
        }
    }
    const float* she = sh + e * 9;
    float* orow = out + (long)dst * 144;
    #pragma unroll
    for (int v = 0; v < 16; ++v) atomicAdd(&orow[v], acc[v] * she[0]);
    #pragma unroll
    for (int v = 0; v < 16; ++v)
        for (int m = 0; m < 3; ++m)
            atomicAdd(&orow[16 + v * 3 + m], acc[16 + v] * she[1 + m]);
    #pragma unroll
    for (int v = 0; v < 16; ++v)
        for (int m = 0; m < 5; ++m)
            atomicAdd(&orow[64 + v * 5 + m], acc[32 + v] * she[4 + m]);
}

// ---------------------------------------------------------------------------

extern "C" void kernel_launch(void* const* d_in, const int* in_sizes, int n_in,
                              void* d_out, int out_size, void* d_ws, size_t ws_size,
                              hipStream_t stream) {
    const float* nf     = (const float*)d_in[0];
    const int*   ei     = (const int*)  d_in[1];
    const float* sh     = (const float*)d_in[2];
    const float* radial = (const float*)d_in[3];
    const float* W1     = (const float*)d_in[4];
    const float* W2     = (const float*)d_in[5];
    const float* Wsi    = (const float*)d_in[6];
    float* out = (float*)d_out;

    const int N = in_sizes[0] / 16;
    const int E = in_sizes[1] / 2;

    size_t mix_bytes  = (size_t)E * 48 * sizeof(float);
    size_t offs_bytes = (size_t)(N + 1) * sizeof(int);
    size_t curs_bytes = (size_t)N * sizeof(int);
    size_t eord_bytes = (size_t)E * sizeof(int);
    size_t bfrag_off  = (mix_bytes + offs_bytes + curs_bytes + eord_bytes + 15) & ~(size_t)15;
    size_t bfrag_bytes = 96 * 512 * sizeof(_Float16);   // 96 KB
    size_t need = bfrag_off + bfrag_bytes;

    if (ws_size < need) {
        int total = N * 144;
        hipLaunchKernelGGL(si_init_kernel, dim3((total + 255) / 256), dim3(256), 0, stream,
                           nf, Wsi, out, N);
        hipLaunchKernelGGL(edge_kernel_atomic, dim3((E + 255) / 256), dim3(256), 0, stream,
                           nf, ei, sh, radial, W1, W2, out, E);
        return;
    }

    float* mix  = (float*)d_ws;
    int*   offs = (int*)((char*)d_ws + mix_bytes);
    int*   curs = (int*)((char*)d_ws + mix_bytes + offs_bytes);
    int*   eord = (int*)((char*)d_ws + mix_bytes + offs_bytes + curs_bytes);
    _Float16* bfrag = (_Float16*)((char*)d_ws + bfrag_off);

    (void)hipMemsetAsync(offs, 0, offs_bytes + curs_bytes, stream);

    int eb = (E + 255) / 256;
    hipLaunchKernelGGL(bfrag_prep_kernel, dim3(192), dim3(256), 0, stream, W2, bfrag);
    hipLaunchKernelGGL(hist_kernel, dim3(eb), dim3(256), 0, stream, ei, offs, E);
    hipLaunchKernelGGL(scan_kernel, dim3(1), dim3(1024), 0, stream, offs, N + 1);
    hipLaunchKernelGGL(scatter_kernel, dim3(eb), dim3(256), 0, stream, ei, offs, curs, eord, E);

    int mblocks = (E + 255) / 256;
    hipLaunchKernelGGL(edge_mfma_kernel, dim3(mblocks), dim3(256), 0, stream,
                       nf, ei, radial, W1, bfrag, mix, E);
    hipLaunchKernelGGL(gather_kernel, dim3((N + 3) / 4), dim3(256), 0, stream,
                       mix, sh, eord, offs, nf, Wsi, out, N);
}

// Round 6
// 196.987 us; speedup vs baseline: 1.1057x; 1.1057x over previous
//
#include <hip/hip_runtime.h>

// ---------------------------------------------------------------------------
// SE3 conv layer. CSR-built scatter (no f32 atomics) + f16-MFMA edge compute.
//   mix[csr_pos(e), lv] = sum_{ku} y[e,ku] * W2r[ku, lv],  y = h(e,k)*x(e,u)
//   h = silu(radial @ W1/4);  W2r pre-packed (scaled 1/32) as f16 B-fragments.
// Phase 1: lane = edge (coalesced radial, W1^T broadcast from LDS).
// Edge kernel writes mix rows in CSR order (pos[e]) -> gather reads linearly.
// ws: [ mix E*48 f32 | offs N+1 | curs N | eord E | pos E | (align) Bfrag 96KB ]
// ---------------------------------------------------------------------------

typedef _Float16 f16x2 __attribute__((ext_vector_type(2)));
typedef _Float16 f16x8 __attribute__((ext_vector_type(8)));
typedef __fp16  g16x2 __attribute__((ext_vector_type(2)));   // cvt_pkrtz result type
typedef float f32x4 __attribute__((ext_vector_type(4)));

union AFrag { unsigned int u[4]; f16x2 h2[4]; f16x8 v; };
union BFrag { uint4 u4; f16x8 v; };
union HW { g16x2 g; f16x2 f; unsigned int u; };

// ---------------------------- CSR build ------------------------------------

__global__ __launch_bounds__(256)
void hist_kernel(const int* __restrict__ ei, int* __restrict__ counts, int E) {
    int e = blockIdx.x * blockDim.x + threadIdx.x;
    if (e < E) atomicAdd(&counts[ei[E + e] + 1], 1);
}

// chunk-serial scan: 1 block, each thread owns ceil(n/1024) contiguous elems.
__global__ __launch_bounds__(1024)
void scan_kernel(int* __restrict__ data, int n) {
    __shared__ int wsum[16];
    int tid = threadIdx.x, lane = tid & 63, wid = tid >> 6;
    int ch = (n + 1023) >> 10;
    int beg = tid * ch;
    int end = beg + ch; if (end > n) end = n;

    int s = 0;
    for (int i = beg; i < end; ++i) s += data[i];

    int v = s;
    #pragma unroll
    for (int off = 1; off < 64; off <<= 1) {
        int t = __shfl_up(v, off, 64);
        if (lane >= off) v += t;
    }
    if (lane == 63) wsum[wid] = v;
    __syncthreads();
    if (wid == 0 && lane < 16) {
        int w = wsum[lane];
        #pragma unroll
        for (int off = 1; off < 16; off <<= 1) {
            int t = __shfl_up(w, off, 16);
            if (lane >= off) w += t;
        }
        wsum[lane] = w;
    }
    __syncthreads();
    int run = (v - s) + (wid > 0 ? wsum[wid - 1] : 0);   // exclusive offset
    for (int i = beg; i < end; ++i) {
        run += data[i];
        data[i] = run;
    }
}

__global__ __launch_bounds__(256)
void scatter_kernel(const int* __restrict__ ei, const int* __restrict__ offs,
                    int* __restrict__ cursor, int* __restrict__ eord,
                    int* __restrict__ pos, int E) {
    int e = blockIdx.x * blockDim.x + threadIdx.x;
    if (e >= E) return;
    int dst = ei[E + e];
    int p = offs[dst] + atomicAdd(&cursor[dst], 1);
    eord[p] = e;
    pos[e] = p;
}

// ------------------------- B-fragment pre-pack (f16) -----------------------
// Bfrag[f][lane][j], f = ks*3+nt, ku = ks*32 + (lane>>4)*8 + j,
// k=ku>>4, u=ku&15, n = nt*16 + (lane&15), l=n>>4, v=n&15; val = W2/32.

__global__ __launch_bounds__(256)
void bfrag_prep_kernel(const float* __restrict__ W2, _Float16* __restrict__ bfrag) {
    int t = blockIdx.x * 256 + threadIdx.x;
    if (t >= 96 * 512) return;
    int f = t >> 9;
    int rr = t & 511;
    int lane = rr >> 3, j = rr & 7;
    int ks = f / 3, nt = f - 3 * ks;
    int q = lane >> 4, c = lane & 15;
    int ku = ks * 32 + q * 8 + j;
    int k = ku >> 4, u = ku & 15;
    int n = nt * 16 + c;
    int l = n >> 4, v = n & 15;
    float val = W2[(size_t)k * 768 + l * 256 + u * 16 + v] * 0.03125f;
    bfrag[t] = (_Float16)val;
}

// --------------------------- MFMA edge kernel ------------------------------
// block = 256 = 4 waves; wave owns 64 edges (4 M-tiles of 16).

__global__ __launch_bounds__(256)
void edge_mfma_kernel(const float* __restrict__ nf, const int* __restrict__ ei,
                      const float* __restrict__ radial, const float* __restrict__ W1,
                      const _Float16* __restrict__ bfrag, const int* __restrict__ pos,
                      float* __restrict__ mixs, int E) {
    __shared__ unsigned int h_lds[4][64][32];   // f16 pairs (k=2t,2t+1), XOR-swizzled
    __shared__ float w1t[64][16];               // W1^T, pre-scaled by 1/4

    int tid = threadIdx.x;

    // stage W1^T (scaled) into LDS once per block
    for (int idx = tid; idx < 1024; idx += 256) {
        int k = idx >> 4, u = idx & 15;
        w1t[k][u] = W1[u * 64 + k] * 0.25f;
    }
    __syncthreads();

    int wave = tid >> 6;
    int lane = tid & 63;
    int r_ = lane & 15;
    int q  = lane >> 4;
    int qh = q >> 1;                 // which half of the h-pair this lane needs
    int ul = (q & 1) * 8;            // u base for A-frag
    unsigned int sel = qh ? 0x03020302u : 0x01000100u;   // v_perm dup selector

    int ebase = blockIdx.x * 256 + wave * 64;

    // ---- phase 1: lane = edge; k-loop with W1^T broadcast reads ----
    {
        int e = ebase + lane; if (e >= E) e = E - 1;
        const float* rp = radial + (size_t)e * 16;
        float4 r0 = *(const float4*)(rp);
        float4 r1 = *(const float4*)(rp + 4);
        float4 r2 = *(const float4*)(rp + 8);
        float4 r3 = *(const float4*)(rp + 12);
        int swz = lane & 31;
        float hprev = 0.0f;
        #pragma unroll 8
        for (int k = 0; k < 64; ++k) {
            const float4* wr = (const float4*)(&w1t[k][0]);
            float4 w0 = wr[0], w1v = wr[1], w2v = wr[2], w3v = wr[3];
            float z = r0.x * w0.x;
            z = fmaf(r0.y, w0.y, z);  z = fmaf(r0.z, w0.z, z);  z = fmaf(r0.w, w0.w, z);
            z = fmaf(r1.x, w1v.x, z); z = fmaf(r1.y, w1v.y, z); z = fmaf(r1.z, w1v.z, z); z = fmaf(r1.w, w1v.w, z);
            z = fmaf(r2.x, w2v.x, z); z = fmaf(r2.y, w2v.y, z); z = fmaf(r2.z, w2v.z, z); z = fmaf(r2.w, w2v.w, z);
            z = fmaf(r3.x, w3v.x, z); z = fmaf(r3.y, w3v.y, z); z = fmaf(r3.z, w3v.z, z); z = fmaf(r3.w, w3v.w, z);
            float h = z * __builtin_amdgcn_rcpf(1.0f + __expf(-z));   // silu
            if (k & 1) {
                HW w; w.g = __builtin_amdgcn_cvt_pkrtz(hprev, h);     // (k-1, k)
                h_lds[wave][lane][(k >> 1) ^ swz] = w.u;
            } else {
                hprev = h;
            }
        }
    }
    // h_lds is per-wave private; within-wave program order suffices (no barrier)

    // ---- phase 2: x rows for the wave's 4 M-tiles, packed f16 ----
    HW xp[4][4];
    #pragma unroll
    for (int m = 0; m < 4; ++m) {
        int e = ebase + m * 16 + r_; if (e >= E) e = E - 1;
        int src = ei[e];
        const float* xpp = nf + (size_t)src * 16 + ul;
        float4 a = *(const float4*)xpp;
        float4 b = *(const float4*)(xpp + 4);
        xp[m][0].g = __builtin_amdgcn_cvt_pkrtz(a.x, a.y);
        xp[m][1].g = __builtin_amdgcn_cvt_pkrtz(a.z, a.w);
        xp[m][2].g = __builtin_amdgcn_cvt_pkrtz(b.x, b.y);
        xp[m][3].g = __builtin_amdgcn_cvt_pkrtz(b.z, b.w);
    }

    // ---- phase 3: K-loop, 32 steps of K=32 ----
    f32x4 acc[4][3];
    #pragma unroll
    for (int m = 0; m < 4; ++m)
        #pragma unroll
        for (int nt = 0; nt < 3; ++nt)
            acc[m][nt] = (f32x4){0.f, 0.f, 0.f, 0.f};

    #pragma unroll 2
    for (int ks = 0; ks < 32; ++ks) {
        BFrag b[3];
        #pragma unroll
        for (int nt = 0; nt < 3; ++nt)
            b[nt].u4 = *(const uint4*)(bfrag + (size_t)(ks * 3 + nt) * 512 + lane * 8);
        #pragma unroll
        for (int m = 0; m < 4; ++m) {
            int el = m * 16 + r_;
            unsigned int hw = h_lds[wave][el][ks ^ (el & 31)];
            HW hv; hv.u = __builtin_amdgcn_perm(hw, hw, sel);  // dup needed half
            AFrag a;
            #pragma unroll
            for (int p2 = 0; p2 < 4; ++p2)
                a.h2[p2] = hv.f * xp[m][p2].f;                 // v_pk_mul_f16
            #pragma unroll
            for (int nt = 0; nt < 3; ++nt)
                acc[m][nt] = __builtin_amdgcn_mfma_f32_16x16x32_f16(a.v, b[nt].v, acc[m][nt], 0, 0, 0);
        }
    }

    // ---- epilogue: C layout col=lane&15, row=(lane>>4)*4+i; write CSR-sorted ----
    #pragma unroll
    for (int m = 0; m < 4; ++m) {
        #pragma unroll
        for (int i = 0; i < 4; ++i) {
            int e = ebase + m * 16 + q * 4 + i;
            if (e < E) {
                int p = pos[e];
                float* mp = mixs + (size_t)p * 48 + r_;
                mp[0]  = acc[m][0][i];
                mp[16] = acc[m][1][i];
                mp[32] = acc[m][2][i];
            }
        }
    }
}

// ------------------------------ gather -------------------------------------
// mix rows are already in CSR order -> linear reads; sh gathered via eord.

__global__ __launch_bounds__(256)
void gather_kernel(const float* __restrict__ mixs, const float* __restrict__ sh,
                   const int* __restrict__ eord, const int* __restrict__ offs,
                   const float* __restrict__ nf, const float* __restrict__ Wsi,
                   float* __restrict__ out, int N) {
    int node = blockIdx.x * 4 + (threadIdx.x >> 6);
    if (node >= N) return;
    int lane = threadIdx.x & 63;

    auto chmap = [](int c, int& mi, int& si) {
        if (c < 16)      { mi = c;                si = 0; }
        else if (c < 64) { int t = c - 16; mi = 16 + t / 3; si = 1 + t % 3; }
        else             { int t = c - 64; mi = 32 + t / 5; si = 4 + t % 5; }
    };
    int mi0, si0, mi1, si1, mi2 = 0, si2 = 0;
    chmap(lane, mi0, si0);
    chmap(lane + 64, mi1, si1);
    if (lane < 16) chmap(lane + 128, mi2, si2);

    float acc0 = 0.0f, acc1 = 0.0f, acc2 = 0.0f;
    int off = offs[node], end = offs[node + 1];
    for (int i = off; i < end; ++i) {
        const float* m = mixs + (size_t)i * 48;          // linear
        const float* s = sh + (size_t)eord[i] * 9;       // L2-resident gather
        acc0 = fmaf(m[mi0], s[si0], acc0);
        acc1 = fmaf(m[mi1], s[si1], acc1);
        if (lane < 16) acc2 = fmaf(m[mi2], s[si2], acc2);
    }

    if (lane < 16) {
        const float* xr = nf + (size_t)node * 16;
        float si = 0.0f;
        #pragma unroll
        for (int u = 0; u < 16; ++u)
            si = fmaf(xr[u], Wsi[u * 16 + lane], si);
        acc0 = fmaf(si, 0.25f, acc0);
    }

    float* orow = out + (size_t)node * 144;
    orow[lane] = acc0;
    orow[lane + 64] = acc1;
    if (lane < 16) orow[lane + 128] = acc2;
}

// ------------------------- fallback (atomic path) --------------------------

__global__ __launch_bounds__(256)
void si_init_kernel(const float* __restrict__ nf, const float* __restrict__ Wsi,
                    float* __restrict__ out, int N) {
    int t = blockIdx.x * blockDim.x + threadIdx.x;
    int total = N * 144;
    if (t >= total) return;
    int n = t / 144;
    int c = t - n * 144;
    float val = 0.0f;
    if (c < 16) {
        const float* xr = nf + n * 16;
        #pragma unroll
        for (int u = 0; u < 16; ++u)
            val = fmaf(xr[u], Wsi[u * 16 + c], val);
        val *= 0.25f;
    }
    out[t] = val;
}

__global__ __launch_bounds__(256)
void edge_kernel_atomic(const float* __restrict__ nf, const int* __restrict__ ei,
                        const float* __restrict__ sh, const float* __restrict__ radial,
                        const float* __restrict__ W1, const float* __restrict__ W2,
                        float* __restrict__ out, int E) {
    int e = blockIdx.x * blockDim.x + threadIdx.x;
    if (e >= E) return;
    int src = ei[e];
    int dst = ei[E + e];
    float r[16], x[16];
    #pragma unroll
    for (int u = 0; u < 16; ++u) r[u] = radial[e * 16 + u] * 0.25f;
    #pragma unroll
    for (int u = 0; u < 16; ++u) x[u] = nf[src * 16 + u] * 0.03125f;
    float acc[48];
    #pragma unroll
    for (int j = 0; j < 48; ++j) acc[j] = 0.0f;
    for (int k = 0; k < 64; ++k) {
        float z = 0.0f;
        #pragma unroll
        for (int u = 0; u < 16; ++u) z = fmaf(r[u], W1[u * 64 + k], z);
        float hk = z / (1.0f + __expf(-z));
        const float* w2k = W2 + k * 768;
        #pragma unroll 4
        for (int u = 0; u < 16; ++u) {
            float p = hk * x[u];
            const float* w = w2k + u * 16;
            #pragma unroll
            for (int l = 0; l < 3; ++l)
                #pragma unroll
                for (int v = 0; v < 16; ++v)
                    acc[l * 16 + v] = fmaf(p, w[l * 256 + v], acc[l * 16 + v]);
        }
    }
    const float* she = sh + e * 9;
    float* orow = out + (long)dst * 144;
    #pragma unroll
    for (int v = 0; v < 16; ++v) atomicAdd(&orow[v], acc[v] * she[0]);
    #pragma unroll
    for (int v = 0; v < 16; ++v)
        for (int m = 0; m < 3; ++m)
            atomicAdd(&orow[16 + v * 3 + m], acc[16 + v] * she[1 + m]);
    #pragma unroll
    for (int v = 0; v < 16; ++v)
        for (int m = 0; m < 5; ++m)
            atomicAdd(&orow[64 + v * 5 + m], acc[32 + v] * she[4 + m]);
}

// ---------------------------------------------------------------------------

extern "C" void kernel_launch(void* const* d_in, const int* in_sizes, int n_in,
                              void* d_out, int out_size, void* d_ws, size_t ws_size,
                              hipStream_t stream) {
    const float* nf     = (const float*)d_in[0];
    const int*   ei     = (const int*)  d_in[1];
    const float* sh     = (const float*)d_in[2];
    const float* radial = (const float*)d_in[3];
    const float* W1     = (const float*)d_in[4];
    const float* W2     = (const float*)d_in[5];
    const float* Wsi    = (const float*)d_in[6];
    float* out = (float*)d_out;

    const int N = in_sizes[0] / 16;
    const int E = in_sizes[1] / 2;

    size_t mix_bytes  = (size_t)E * 48 * sizeof(float);
    size_t offs_bytes = (size_t)(N + 1) * sizeof(int);
    size_t curs_bytes = (size_t)N * sizeof(int);
    size_t eord_bytes = (size_t)E * sizeof(int);
    size_t pos_bytes  = (size_t)E * sizeof(int);
    size_t bfrag_off  = (mix_bytes + offs_bytes + curs_bytes + eord_bytes + pos_bytes + 15) & ~(size_t)15;
    size_t bfrag_bytes = 96 * 512 * sizeof(_Float16);   // 96 KB
    size_t need = bfrag_off + bfrag_bytes;

    if (ws_size < need) {
        int total = N * 144;
        hipLaunchKernelGGL(si_init_kernel, dim3((total + 255) / 256), dim3(256), 0, stream,
                           nf, Wsi, out, N);
        hipLaunchKernelGGL(edge_kernel_atomic, dim3((E + 255) / 256), dim3(256), 0, stream,
                           nf, ei, sh, radial, W1, W2, out, E);
        return;
    }

    float* mixs = (float*)d_ws;
    int*   offs = (int*)((char*)d_ws + mix_bytes);
    int*   curs = (int*)((char*)d_ws + mix_bytes + offs_bytes);
    int*   eord = (int*)((char*)d_ws + mix_bytes + offs_bytes + curs_bytes);
    int*   pos  = (int*)((char*)d_ws + mix_bytes + offs_bytes + curs_bytes + eord_bytes);
    _Float16* bfrag = (_Float16*)((char*)d_ws + bfrag_off);

    (void)hipMemsetAsync(offs, 0, offs_bytes + curs_bytes, stream);

    int eb = (E + 255) / 256;
    hipLaunchKernelGGL(bfrag_prep_kernel, dim3(192), dim3(256), 0, stream, W2, bfrag);
    hipLaunchKernelGGL(hist_kernel, dim3(eb), dim3(256), 0, stream, ei, offs, E);
    hipLaunchKernelGGL(scan_kernel, dim3(1), dim3(1024), 0, stream, offs, N + 1);
    hipLaunchKernelGGL(scatter_kernel, dim3(eb), dim3(256), 0, stream, ei, offs, curs, eord, pos, E);

    int mblocks = (E + 255) / 256;
    hipLaunchKernelGGL(edge_mfma_kernel, dim3(mblocks), dim3(256), 0, stream,
                       nf, ei, radial, W1, bfrag, pos, mixs, E);
    hipLaunchKernelGGL(gather_kernel, dim3((N + 3) / 4), dim3(256), 0, stream,
                       mixs, sh, eord, offs, nf, Wsi, out, N);
}

// Round 7
// 181.442 us; speedup vs baseline: 1.2004x; 1.0857x over previous
//
#include <hip/hip_runtime.h>

// ---------------------------------------------------------------------------
// SE3 conv layer. CSR-built scatter (no f32 atomics) + f16-MFMA edge compute.
//   mix[csr_pos(e), lv] = sum_{ku} y[e,ku] * W2r[ku, lv],  y = h(e,k)*x(e,u)
//   h = silu(radial @ W1/4);  W2r pre-packed (scaled 1/32) as f16 B-fragments.
// scatter also copies sh rows into CSR order (shs) -> gather is fully linear.
// ws: [ mix E*48 f32 | offs N+1 | curs N | pos E | shs E*9 f32 | (align) Bfrag ]
// ---------------------------------------------------------------------------

typedef _Float16 f16x2 __attribute__((ext_vector_type(2)));
typedef _Float16 f16x8 __attribute__((ext_vector_type(8)));
typedef __fp16  g16x2 __attribute__((ext_vector_type(2)));   // cvt_pkrtz result type
typedef float f32x4 __attribute__((ext_vector_type(4)));

union AFrag { unsigned int u[4]; f16x2 h2[4]; f16x8 v; };
union BFrag { uint4 u4; f16x8 v; };
union HW { g16x2 g; f16x2 f; unsigned int u; };

// ---------------------------- CSR build ------------------------------------

__global__ __launch_bounds__(256)
void hist_kernel(const int* __restrict__ ei, int* __restrict__ counts, int E) {
    int e = blockIdx.x * blockDim.x + threadIdx.x;
    if (e < E) atomicAdd(&counts[ei[E + e] + 1], 1);
}

// chunk-serial scan: 1 block, each thread owns ceil(n/1024) contiguous elems.
__global__ __launch_bounds__(1024)
void scan_kernel(int* __restrict__ data, int n) {
    __shared__ int wsum[16];
    int tid = threadIdx.x, lane = tid & 63, wid = tid >> 6;
    int ch = (n + 1023) >> 10;
    int beg = tid * ch;
    int end = beg + ch; if (end > n) end = n;

    int s = 0;
    for (int i = beg; i < end; ++i) s += data[i];

    int v = s;
    #pragma unroll
    for (int off = 1; off < 64; off <<= 1) {
        int t = __shfl_up(v, off, 64);
        if (lane >= off) v += t;
    }
    if (lane == 63) wsum[wid] = v;
    __syncthreads();
    if (wid == 0 && lane < 16) {
        int w = wsum[lane];
        #pragma unroll
        for (int off = 1; off < 16; off <<= 1) {
            int t = __shfl_up(w, off, 16);
            if (lane >= off) w += t;
        }
        wsum[lane] = w;
    }
    __syncthreads();
    int run = (v - s) + (wid > 0 ? wsum[wid - 1] : 0);   // exclusive offset
    for (int i = beg; i < end; ++i) {
        run += data[i];
        data[i] = run;
    }
}

// scatter: compute CSR position, record pos[e], and copy sh row to CSR order.
__global__ __launch_bounds__(256)
void scatter_kernel(const int* __restrict__ ei, const float* __restrict__ sh,
                    const int* __restrict__ offs, int* __restrict__ cursor,
                    int* __restrict__ pos, float* __restrict__ shs, int E) {
    int e = blockIdx.x * blockDim.x + threadIdx.x;
    if (e >= E) return;
    int dst = ei[E + e];
    int p = offs[dst] + atomicAdd(&cursor[dst], 1);
    pos[e] = p;
    const float* s = sh + (size_t)e * 9;     // coalesced-ish read
    float* d = shs + (size_t)p * 9;          // scattered write (fire-and-forget)
    #pragma unroll
    for (int j = 0; j < 9; ++j) d[j] = s[j];
}

// ------------------------- B-fragment pre-pack (f16) -----------------------
// Bfrag[f][lane][j], f = ks*3+nt, ku = ks*32 + (lane>>4)*8 + j,
// k=ku>>4, u=ku&15, n = nt*16 + (lane&15), l=n>>4, v=n&15; val = W2/32.

__global__ __launch_bounds__(256)
void bfrag_prep_kernel(const float* __restrict__ W2, _Float16* __restrict__ bfrag) {
    int t = blockIdx.x * 256 + threadIdx.x;
    if (t >= 96 * 512) return;
    int f = t >> 9;
    int rr = t & 511;
    int lane = rr >> 3, j = rr & 7;
    int ks = f / 3, nt = f - 3 * ks;
    int q = lane >> 4, c = lane & 15;
    int ku = ks * 32 + q * 8 + j;
    int k = ku >> 4, u = ku & 15;
    int n = nt * 16 + c;
    int l = n >> 4, v = n & 15;
    float val = W2[(size_t)k * 768 + l * 256 + u * 16 + v] * 0.03125f;
    bfrag[t] = (_Float16)val;
}

// --------------------------- MFMA edge kernel ------------------------------
// block = 256 = 4 waves; wave owns 64 edges (4 M-tiles of 16).

__global__ __launch_bounds__(256, 4)
void edge_mfma_kernel(const float* __restrict__ nf, const int* __restrict__ ei,
                      const float* __restrict__ radial, const float* __restrict__ W1,
                      const _Float16* __restrict__ bfrag, const int* __restrict__ pos,
                      float* __restrict__ mixs, int E) {
    __shared__ unsigned int h_lds[4][64][32];   // f16 pairs (k=2t,2t+1), XOR-swizzled
    __shared__ float w1t[64][16];               // W1^T, pre-scaled by 1/4

    int tid = threadIdx.x;

    // stage W1^T (scaled) into LDS once per block
    for (int idx = tid; idx < 1024; idx += 256) {
        int k = idx >> 4, u = idx & 15;
        w1t[k][u] = W1[u * 64 + k] * 0.25f;
    }
    __syncthreads();

    int wave = tid >> 6;
    int lane = tid & 63;
    int r_ = lane & 15;
    int q  = lane >> 6 ? 0 : lane >> 4;          // q = lane>>4 (0..3)
    q = lane >> 4;
    int qh = q >> 1;                 // which half of the h-pair this lane needs
    int ul = (q & 1) * 8;            // u base for A-frag
    unsigned int sel = qh ? 0x03020302u : 0x01000100u;   // v_perm dup selector

    int ebase = blockIdx.x * 256 + wave * 64;

    // ---- phase 0: x rows for the wave's 4 M-tiles (issue early), f16 pack ----
    HW xp[4][4];
    #pragma unroll
    for (int m = 0; m < 4; ++m) {
        int e = ebase + m * 16 + r_; if (e >= E) e = E - 1;
        int src = ei[e];
        const float* xpp = nf + (size_t)src * 16 + ul;
        float4 a = *(const float4*)xpp;
        float4 b = *(const float4*)(xpp + 4);
        xp[m][0].g = __builtin_amdgcn_cvt_pkrtz(a.x, a.y);
        xp[m][1].g = __builtin_amdgcn_cvt_pkrtz(a.z, a.w);
        xp[m][2].g = __builtin_amdgcn_cvt_pkrtz(b.x, b.y);
        xp[m][3].g = __builtin_amdgcn_cvt_pkrtz(b.z, b.w);
    }

    // ---- phase 1: lane = edge; k-loop with W1^T broadcast reads ----
    {
        int e = ebase + lane; if (e >= E) e = E - 1;
        const float* rp = radial + (size_t)e * 16;
        float4 r0 = *(const float4*)(rp);
        float4 r1 = *(const float4*)(rp + 4);
        float4 r2 = *(const float4*)(rp + 8);
        float4 r3 = *(const float4*)(rp + 12);
        int swz = lane & 31;
        float hprev = 0.0f;
        #pragma unroll 8
        for (int k = 0; k < 64; ++k) {
            const float4* wr = (const float4*)(&w1t[k][0]);
            float4 w0 = wr[0], w1v = wr[1], w2v = wr[2], w3v = wr[3];
            float z = r0.x * w0.x;
            z = fmaf(r0.y, w0.y, z);  z = fmaf(r0.z, w0.z, z);  z = fmaf(r0.w, w0.w, z);
            z = fmaf(r1.x, w1v.x, z); z = fmaf(r1.y, w1v.y, z); z = fmaf(r1.z, w1v.z, z); z = fmaf(r1.w, w1v.w, z);
            z = fmaf(r2.x, w2v.x, z); z = fmaf(r2.y, w2v.y, z); z = fmaf(r2.z, w2v.z, z); z = fmaf(r2.w, w2v.w, z);
            z = fmaf(r3.x, w3v.x, z); z = fmaf(r3.y, w3v.y, z); z = fmaf(r3.z, w3v.z, z); z = fmaf(r3.w, w3v.w, z);
            float h = z * __builtin_amdgcn_rcpf(1.0f + __expf(-z));   // silu
            if (k & 1) {
                HW w; w.g = __builtin_amdgcn_cvt_pkrtz(hprev, h);     // (k-1, k)
                h_lds[wave][lane][(k >> 1) ^ swz] = w.u;
            } else {
                hprev = h;
            }
        }
    }
    // h_lds is per-wave private; within-wave program order suffices (no barrier)

    // ---- phase 3: K-loop, 32 steps of K=32 ----
    f32x4 acc[4][3];
    #pragma unroll
    for (int m = 0; m < 4; ++m)
        #pragma unroll
        for (int nt = 0; nt < 3; ++nt)
            acc[m][nt] = (f32x4){0.f, 0.f, 0.f, 0.f};

    #pragma unroll 2
    for (int ks = 0; ks < 32; ++ks) {
        BFrag b[3];
        #pragma unroll
        for (int nt = 0; nt < 3; ++nt)
            b[nt].u4 = *(const uint4*)(bfrag + (size_t)(ks * 3 + nt) * 512 + lane * 8);
        #pragma unroll
        for (int m = 0; m < 4; ++m) {
            int el = m * 16 + r_;
            unsigned int hw = h_lds[wave][el][ks ^ (el & 31)];
            HW hv; hv.u = __builtin_amdgcn_perm(hw, hw, sel);  // dup needed half
            AFrag a;
            #pragma unroll
            for (int p2 = 0; p2 < 4; ++p2)
                a.h2[p2] = hv.f * xp[m][p2].f;                 // v_pk_mul_f16
            #pragma unroll
            for (int nt = 0; nt < 3; ++nt)
                acc[m][nt] = __builtin_amdgcn_mfma_f32_16x16x32_f16(a.v, b[nt].v, acc[m][nt], 0, 0, 0);
        }
    }

    // ---- epilogue: C layout col=lane&15, row=(lane>>4)*4+i; write CSR-sorted ----
    #pragma unroll
    for (int m = 0; m < 4; ++m) {
        #pragma unroll
        for (int i = 0; i < 4; ++i) {
            int e = ebase + m * 16 + q * 4 + i;
            if (e < E) {
                int p = pos[e];
                float* mp = mixs + (size_t)p * 48 + r_;
                mp[0]  = acc[m][0][i];
                mp[16] = acc[m][1][i];
                mp[32] = acc[m][2][i];
            }
        }
    }
}

// ------------------------------ gather -------------------------------------
// mix and sh rows are both in CSR order -> fully linear reads, no indices.

__global__ __launch_bounds__(256)
void gather_kernel(const float* __restrict__ mixs, const float* __restrict__ shs,
                   const int* __restrict__ offs,
                   const float* __restrict__ nf, const float* __restrict__ Wsi,
                   float* __restrict__ out, int N) {
    int node = blockIdx.x * 4 + (threadIdx.x >> 6);
    if (node >= N) return;
    int lane = threadIdx.x & 63;

    auto chmap = [](int c, int& mi, int& si) {
        if (c < 16)      { mi = c;                si = 0; }
        else if (c < 64) { int t = c - 16; mi = 16 + t / 3; si = 1 + t % 3; }
        else             { int t = c - 64; mi = 32 + t / 5; si = 4 + t % 5; }
    };
    int mi0, si0, mi1, si1, mi2 = 0, si2 = 0;
    chmap(lane, mi0, si0);
    chmap(lane + 64, mi1, si1);
    if (lane < 16) chmap(lane + 128, mi2, si2);

    float acc0 = 0.0f, acc1 = 0.0f, acc2 = 0.0f;
    int off = offs[node], end = offs[node + 1];
    #pragma unroll 2
    for (int i = off; i < end; ++i) {
        const float* m = mixs + (size_t)i * 48;   // linear
        const float* s = shs + (size_t)i * 9;     // linear
        acc0 = fmaf(m[mi0], s[si0], acc0);
        acc1 = fmaf(m[mi1], s[si1], acc1);
        if (lane < 16) acc2 = fmaf(m[mi2], s[si2], acc2);
    }

    if (lane < 16) {
        const float* xr = nf + (size_t)node * 16;
        float si = 0.0f;
        #pragma unroll
        for (int u = 0; u < 16; ++u)
            si = fmaf(xr[u], Wsi[u * 16 + lane], si);
        acc0 = fmaf(si, 0.25f, acc0);
    }

    float* orow = out + (size_t)node * 144;
    orow[lane] = acc0;
    orow[lane + 64] = acc1;
    if (lane < 16) orow[lane + 128] = acc2;
}

// ------------------------- fallback (atomic path) --------------------------

__global__ __launch_bounds__(256)
void si_init_kernel(const float* __restrict__ nf, const float* __restrict__ Wsi,
                    float* __restrict__ out, int N) {
    int t = blockIdx.x * blockDim.x + threadIdx.x;
    int total = N * 144;
    if (t >= total) return;
    int n = t / 144;
    int c = t - n * 144;
    float val = 0.0f;
    if (c < 16) {
        const float* xr = nf + n * 16;
        #pragma unroll
        for (int u = 0; u < 16; ++u)
            val = fmaf(xr[u], Wsi[u * 16 + c], val);
        val *= 0.25f;
    }
    out[t] = val;
}

__global__ __launch_bounds__(256)
void edge_kernel_atomic(const float* __restrict__ nf, const int* __restrict__ ei,
                        const float* __restrict__ sh, const float* __restrict__ radial,
                        const float* __restrict__ W1, const float* __restrict__ W2,
                        float* __restrict__ out, int E) {
    int e = blockIdx.x * blockDim.x + threadIdx.x;
    if (e >= E) return;
    int src = ei[e];
    int dst = ei[E + e];
    float r[16], x[16];
    #pragma unroll
    for (int u = 0; u < 16; ++u) r[u] = radial[e * 16 + u] * 0.25f;
    #pragma unroll
    for (int u = 0; u < 16; ++u) x[u] = nf[src * 16 + u] * 0.03125f;
    float acc[48];
    #pragma unroll
    for (int j = 0; j < 48; ++j) acc[j] = 0.0f;
    for (int k = 0; k < 64; ++k) {
        float z = 0.0f;
        #pragma unroll
        for (int u = 0; u < 16; ++u) z = fmaf(r[u], W1[u * 64 + k], z);
        float hk = z / (1.0f + __expf(-z));
        const float* w2k = W2 + k * 768;
        #pragma unroll 4
        for (int u = 0; u < 16; ++u) {
            float p = hk * x[u];
            const float* w = w2k + u * 16;
            #pragma unroll
            for (int l = 0; l < 3; ++l)
                #pragma unroll
                for (int v = 0; v < 16; ++v)
                    acc[l * 16 + v] = fmaf(p, w[l * 256 + v], acc[l * 16 + v]);
        }
    }
    const float* she = sh + e * 9;
    float* orow = out + (long)dst * 144;
    #pragma unroll
    for (int v = 0; v < 16; ++v) atomicAdd(&orow[v], acc[v] * she[0]);
    #pragma unroll
    for (int v = 0; v < 16; ++v)
        for (int m = 0; m < 3; ++m)
            atomicAdd(&orow[16 + v * 3 + m], acc[16 + v] * she[1 + m]);
    #pragma unroll
    for (int v = 0; v < 16; ++v)
        for (int m = 0; m < 5; ++m)
            atomicAdd(&orow[64 + v * 5 + m], acc[32 + v] * she[4 + m]);
}

// ---------------------------------------------------------------------------

extern "C" void kernel_launch(void* const* d_in, const int* in_sizes, int n_in,
                              void* d_out, int out_size, void* d_ws, size_t ws_size,
                              hipStream_t stream) {
    const float* nf     = (const float*)d_in[0];
    const int*   ei     = (const int*)  d_in[1];
    const float* sh     = (const float*)d_in[2];
    const float* radial = (const float*)d_in[3];
    const float* W1     = (const float*)d_in[4];
    const float* W2     = (const float*)d_in[5];
    const float* Wsi    = (const float*)d_in[6];
    float* out = (float*)d_out;

    const int N = in_sizes[0] / 16;
    const int E = in_sizes[1] / 2;

    size_t mix_bytes  = (size_t)E * 48 * sizeof(float);
    size_t offs_bytes = (size_t)(N + 1) * sizeof(int);
    size_t curs_bytes = (size_t)N * sizeof(int);
    size_t pos_bytes  = (size_t)E * sizeof(int);
    size_t shs_bytes  = (size_t)E * 9 * sizeof(float);
    size_t bfrag_off  = (mix_bytes + offs_bytes + curs_bytes + pos_bytes + shs_bytes + 15) & ~(size_t)15;
    size_t bfrag_bytes = 96 * 512 * sizeof(_Float16);   // 96 KB
    size_t need = bfrag_off + bfrag_bytes;

    if (ws_size < need) {
        int total = N * 144;
        hipLaunchKernelGGL(si_init_kernel, dim3((total + 255) / 256), dim3(256), 0, stream,
                           nf, Wsi, out, N);
        hipLaunchKernelGGL(edge_kernel_atomic, dim3((E + 255) / 256), dim3(256), 0, stream,
                           nf, ei, sh, radial, W1, W2, out, E);
        return;
    }

    char* wsb = (char*)d_ws;
    float* mixs = (float*)wsb;
    int*   offs = (int*)(wsb + mix_bytes);
    int*   curs = (int*)(wsb + mix_bytes + offs_bytes);
    int*   pos  = (int*)(wsb + mix_bytes + offs_bytes + curs_bytes);
    float* shs  = (float*)(wsb + mix_bytes + offs_bytes + curs_bytes + pos_bytes);
    _Float16* bfrag = (_Float16*)(wsb + bfrag_off);

    (void)hipMemsetAsync(offs, 0, offs_bytes + curs_bytes, stream);

    int eb = (E + 255) / 256;
    hipLaunchKernelGGL(bfrag_prep_kernel, dim3(192), dim3(256), 0, stream, W2, bfrag);
    hipLaunchKernelGGL(hist_kernel, dim3(eb), dim3(256), 0, stream, ei, offs, E);
    hipLaunchKernelGGL(scan_kernel, dim3(1), dim3(1024), 0, stream, offs, N + 1);
    hipLaunchKernelGGL(scatter_kernel, dim3(eb), dim3(256), 0, stream,
                       ei, sh, offs, curs, pos, shs, E);

    int mblocks = (E + 255) / 256;
    hipLaunchKernelGGL(edge_mfma_kernel, dim3(mblocks), dim3(256), 0, stream,
                       nf, ei, radial, W1, bfrag, pos, mixs, E);
    hipLaunchKernelGGL(gather_kernel, dim3((N + 3) / 4), dim3(256), 0, stream,
                       mixs, shs, offs, nf, Wsi, out, N);
}

// Round 8
// 179.205 us; speedup vs baseline: 1.2154x; 1.0125x over previous
//
#include <hip/hip_runtime.h>

// ---------------------------------------------------------------------------
// SE3 conv layer. CSR-built scatter (no f32 atomics) + f16-MFMA edge compute.
//   mix[csr_pos(e), lv] = sum_{ku} y[e,ku] * W2r[ku, lv],  y = h(e,k)*x(e,u)
//   h = silu(radial @ W1/4);  W2r pre-packed (scaled 1/32) as f16 B-fragments.
// mix stored as f16, 128-B padded rows: bytes 0-63 = (l0[v],l1[v]) u32 pairs,
// bytes 64-95 = l2[v]. scatter copies sh rows into CSR order -> linear gather.
// ws: [ mix E*64 f16 | offs N+1 | curs N | pos E | shs E*9 f32 | (align) Bfrag ]
// ---------------------------------------------------------------------------

typedef _Float16 f16x2 __attribute__((ext_vector_type(2)));
typedef _Float16 f16x8 __attribute__((ext_vector_type(8)));
typedef __fp16  g16x2 __attribute__((ext_vector_type(2)));   // cvt_pkrtz result type
typedef float f32x4 __attribute__((ext_vector_type(4)));

union AFrag { unsigned int u[4]; f16x2 h2[4]; f16x8 v; };
union BFrag { uint4 u4; f16x8 v; };
union HW { g16x2 g; f16x2 f; unsigned int u; };

// ---------------------------- CSR build ------------------------------------

__global__ __launch_bounds__(256)
void hist_kernel(const int* __restrict__ ei, int* __restrict__ counts, int E) {
    int e = blockIdx.x * blockDim.x + threadIdx.x;
    if (e < E) atomicAdd(&counts[ei[E + e] + 1], 1);
}

// chunk-serial scan: 1 block, each thread owns ceil(n/1024) contiguous elems.
__global__ __launch_bounds__(1024)
void scan_kernel(int* __restrict__ data, int n) {
    __shared__ int wsum[16];
    int tid = threadIdx.x, lane = tid & 63, wid = tid >> 6;
    int ch = (n + 1023) >> 10;
    int beg = tid * ch;
    int end = beg + ch; if (end > n) end = n;

    int s = 0;
    for (int i = beg; i < end; ++i) s += data[i];

    int v = s;
    #pragma unroll
    for (int off = 1; off < 64; off <<= 1) {
        int t = __shfl_up(v, off, 64);
        if (lane >= off) v += t;
    }
    if (lane == 63) wsum[wid] = v;
    __syncthreads();
    if (wid == 0 && lane < 16) {
        int w = wsum[lane];
        #pragma unroll
        for (int off = 1; off < 16; off <<= 1) {
            int t = __shfl_up(w, off, 16);
            if (lane >= off) w += t;
        }
        wsum[lane] = w;
    }
    __syncthreads();
    int run = (v - s) + (wid > 0 ? wsum[wid - 1] : 0);   // exclusive offset
    for (int i = beg; i < end; ++i) {
        run += data[i];
        data[i] = run;
    }
}

// scatter: compute CSR position, record pos[e], and copy sh row to CSR order.
__global__ __launch_bounds__(256)
void scatter_kernel(const int* __restrict__ ei, const float* __restrict__ sh,
                    const int* __restrict__ offs, int* __restrict__ cursor,
                    int* __restrict__ pos, float* __restrict__ shs, int E) {
    int e = blockIdx.x * blockDim.x + threadIdx.x;
    if (e >= E) return;
    int dst = ei[E + e];
    int p = offs[dst] + atomicAdd(&cursor[dst], 1);
    pos[e] = p;
    const float* s = sh + (size_t)e * 9;     // coalesced-ish read
    float* d = shs + (size_t)p * 9;          // scattered write (fire-and-forget)
    #pragma unroll
    for (int j = 0; j < 9; ++j) d[j] = s[j];
}

// ------------------------- B-fragment pre-pack (f16) -----------------------
// Bfrag[f][lane][j], f = ks*3+nt, ku = ks*32 + (lane>>4)*8 + j,
// k=ku>>4, u=ku&15, n = nt*16 + (lane&15), l=n>>4, v=n&15; val = W2/32.

__global__ __launch_bounds__(256)
void bfrag_prep_kernel(const float* __restrict__ W2, _Float16* __restrict__ bfrag) {
    int t = blockIdx.x * 256 + threadIdx.x;
    if (t >= 96 * 512) return;
    int f = t >> 9;
    int rr = t & 511;
    int lane = rr >> 3, j = rr & 7;
    int ks = f / 3, nt = f - 3 * ks;
    int q = lane >> 4, c = lane & 15;
    int ku = ks * 32 + q * 8 + j;
    int k = ku >> 4, u = ku & 15;
    int n = nt * 16 + c;
    int l = n >> 4, v = n & 15;
    float val = W2[(size_t)k * 768 + l * 256 + u * 16 + v] * 0.03125f;
    bfrag[t] = (_Float16)val;
}

// --------------------------- MFMA edge kernel ------------------------------
// block = 256 = 4 waves; wave owns 64 edges (4 M-tiles of 16).

__global__ __launch_bounds__(256, 4)
void edge_mfma_kernel(const float* __restrict__ nf, const int* __restrict__ ei,
                      const float* __restrict__ radial, const float* __restrict__ W1,
                      const _Float16* __restrict__ bfrag, const int* __restrict__ pos,
                      _Float16* __restrict__ mixs, int E) {
    __shared__ unsigned int h_lds[4][64][32];   // f16 pairs (k=2t,2t+1), XOR-swizzled
    __shared__ float w1t[64][16];               // W1^T, pre-scaled by 1/4

    int tid = threadIdx.x;

    // stage W1^T (scaled) into LDS once per block
    for (int idx = tid; idx < 1024; idx += 256) {
        int k = idx >> 4, u = idx & 15;
        w1t[k][u] = W1[u * 64 + k] * 0.25f;
    }
    __syncthreads();

    int wave = tid >> 6;
    int lane = tid & 63;
    int r_ = lane & 15;
    int q  = lane >> 4;
    int qh = q >> 1;                 // which half of the h-pair this lane needs
    int ul = (q & 1) * 8;            // u base for A-frag
    unsigned int sel = qh ? 0x03020302u : 0x01000100u;   // v_perm dup selector

    int ebase = blockIdx.x * 256 + wave * 64;

    // ---- phase 0: x rows for the wave's 4 M-tiles (issue early), f16 pack ----
    HW xp[4][4];
    #pragma unroll
    for (int m = 0; m < 4; ++m) {
        int e = ebase + m * 16 + r_; if (e >= E) e = E - 1;
        int src = ei[e];
        const float* xpp = nf + (size_t)src * 16 + ul;
        float4 a = *(const float4*)xpp;
        float4 b = *(const float4*)(xpp + 4);
        xp[m][0].g = __builtin_amdgcn_cvt_pkrtz(a.x, a.y);
        xp[m][1].g = __builtin_amdgcn_cvt_pkrtz(a.z, a.w);
        xp[m][2].g = __builtin_amdgcn_cvt_pkrtz(b.x, b.y);
        xp[m][3].g = __builtin_amdgcn_cvt_pkrtz(b.z, b.w);
    }

    // ---- phase 1: lane = edge; k-loop with W1^T broadcast reads ----
    {
        int e = ebase + lane; if (e >= E) e = E - 1;
        const float* rp = radial + (size_t)e * 16;
        float4 r0 = *(const float4*)(rp);
        float4 r1 = *(const float4*)(rp + 4);
        float4 r2 = *(const float4*)(rp + 8);
        float4 r3 = *(const float4*)(rp + 12);
        int swz = lane & 31;
        float hprev = 0.0f;
        #pragma unroll 8
        for (int k = 0; k < 64; ++k) {
            const float4* wr = (const float4*)(&w1t[k][0]);
            float4 w0 = wr[0], w1v = wr[1], w2v = wr[2], w3v = wr[3];
            float z = r0.x * w0.x;
            z = fmaf(r0.y, w0.y, z);  z = fmaf(r0.z, w0.z, z);  z = fmaf(r0.w, w0.w, z);
            z = fmaf(r1.x, w1v.x, z); z = fmaf(r1.y, w1v.y, z); z = fmaf(r1.z, w1v.z, z); z = fmaf(r1.w, w1v.w, z);
            z = fmaf(r2.x, w2v.x, z); z = fmaf(r2.y, w2v.y, z); z = fmaf(r2.z, w2v.z, z); z = fmaf(r2.w, w2v.w, z);
            z = fmaf(r3.x, w3v.x, z); z = fmaf(r3.y, w3v.y, z); z = fmaf(r3.z, w3v.z, z); z = fmaf(r3.w, w3v.w, z);
            float h = z * __builtin_amdgcn_rcpf(1.0f + __expf(-z));   // silu
            if (k & 1) {
                HW w; w.g = __builtin_amdgcn_cvt_pkrtz(hprev, h);     // (k-1, k)
                h_lds[wave][lane][(k >> 1) ^ swz] = w.u;
            } else {
                hprev = h;
            }
        }
    }
    // h_lds is per-wave private; within-wave program order suffices (no barrier)

    // ---- phase 3: K-loop, 32 steps of K=32 ----
    f32x4 acc[4][3];
    #pragma unroll
    for (int m = 0; m < 4; ++m)
        #pragma unroll
        for (int nt = 0; nt < 3; ++nt)
            acc[m][nt] = (f32x4){0.f, 0.f, 0.f, 0.f};

    #pragma unroll 2
    for (int ks = 0; ks < 32; ++ks) {
        BFrag b[3];
        #pragma unroll
        for (int nt = 0; nt < 3; ++nt)
            b[nt].u4 = *(const uint4*)(bfrag + (size_t)(ks * 3 + nt) * 512 + lane * 8);
        #pragma unroll
        for (int m = 0; m < 4; ++m) {
            int el = m * 16 + r_;
            unsigned int hw = h_lds[wave][el][ks ^ (el & 31)];
            HW hv; hv.u = __builtin_amdgcn_perm(hw, hw, sel);  // dup needed half
            AFrag a;
            #pragma unroll
            for (int p2 = 0; p2 < 4; ++p2)
                a.h2[p2] = hv.f * xp[m][p2].f;                 // v_pk_mul_f16
            #pragma unroll
            for (int nt = 0; nt < 3; ++nt)
                acc[m][nt] = __builtin_amdgcn_mfma_f32_16x16x32_f16(a.v, b[nt].v, acc[m][nt], 0, 0, 0);
        }
    }

    // ---- epilogue: C layout col=lane&15, row=(lane>>4)*4+i; write f16 rows ----
    // row p (128 B): u32[r_] = (l0[r_], l1[r_]) f16 pair; f16[32+r_] = l2[r_]
    unsigned int* mixu = (unsigned int*)mixs;
    #pragma unroll
    for (int m = 0; m < 4; ++m) {
        #pragma unroll
        for (int i = 0; i < 4; ++i) {
            int e = ebase + m * 16 + q * 4 + i;
            if (e < E) {
                int p = pos[e];
                HW pr; pr.g = __builtin_amdgcn_cvt_pkrtz(acc[m][0][i], acc[m][1][i]);
                mixu[(size_t)p * 32 + r_] = pr.u;
                mixs[(size_t)p * 64 + 32 + r_] = (_Float16)acc[m][2][i];
            }
        }
    }
}

// ------------------------------ gather -------------------------------------
// mix (f16, 128-B rows) and sh rows both in CSR order -> fully linear reads.

__global__ __launch_bounds__(256)
void gather_kernel(const _Float16* __restrict__ mixs, const float* __restrict__ shs,
                   const int* __restrict__ offs,
                   const float* __restrict__ nf, const float* __restrict__ Wsi,
                   float* __restrict__ out, int N) {
    int node = blockIdx.x * 4 + (threadIdx.x >> 6);
    if (node >= N) return;
    int lane = threadIdx.x & 63;

    // channel c -> (f16 half-index within 64-half row, sh index)
    auto chmap = [](int c, int& hi, int& si) {
        if (c < 16)      { hi = 2 * c;           si = 0; }
        else if (c < 64) { int t = c - 16; hi = 2 * (t / 3) + 1; si = 1 + t % 3; }
        else             { int t = c - 64; hi = 32 + t / 5;      si = 4 + t % 5; }
    };
    int hi0, si0, hi1, si1, hi2 = 0, si2 = 0;
    chmap(lane, hi0, si0);
    chmap(lane + 64, hi1, si1);
    if (lane < 16) chmap(lane + 128, hi2, si2);

    float a0 = 0.f, a1 = 0.f, a2 = 0.f;
    float b0 = 0.f, b1 = 0.f, b2 = 0.f;
    int off = offs[node], end = offs[node + 1];
    int i = off;
    for (; i + 1 < end; i += 2) {
        const _Float16* m0 = mixs + (size_t)i * 64;
        const _Float16* m1 = mixs + (size_t)(i + 1) * 64;
        const float* s0 = shs + (size_t)i * 9;
        const float* s1 = shs + (size_t)(i + 1) * 9;
        a0 = fmaf((float)m0[hi0], s0[si0], a0);
        b0 = fmaf((float)m1[hi0], s1[si0], b0);
        a1 = fmaf((float)m0[hi1], s0[si1], a1);
        b1 = fmaf((float)m1[hi1], s1[si1], b1);
        if (lane < 16) {
            a2 = fmaf((float)m0[hi2], s0[si2], a2);
            b2 = fmaf((float)m1[hi2], s1[si2], b2);
        }
    }
    if (i < end) {
        const _Float16* m0 = mixs + (size_t)i * 64;
        const float* s0 = shs + (size_t)i * 9;
        a0 = fmaf((float)m0[hi0], s0[si0], a0);
        a1 = fmaf((float)m0[hi1], s0[si1], a1);
        if (lane < 16) a2 = fmaf((float)m0[hi2], s0[si2], a2);
    }
    a0 += b0; a1 += b1; a2 += b2;

    if (lane < 16) {   // self-interaction, 0e->0e only
        const float* xr = nf + (size_t)node * 16;
        float si = 0.0f;
        #pragma unroll
        for (int u = 0; u < 16; ++u)
            si = fmaf(xr[u], Wsi[u * 16 + lane], si);
        a0 = fmaf(si, 0.25f, a0);
    }

    float* orow = out + (size_t)node * 144;
    orow[lane] = a0;
    orow[lane + 64] = a1;
    if (lane < 16) orow[lane + 128] = a2;
}

// ------------------------- fallback (atomic path) --------------------------

__global__ __launch_bounds__(256)
void si_init_kernel(const float* __restrict__ nf, const float* __restrict__ Wsi,
                    float* __restrict__ out, int N) {
    int t = blockIdx.x * blockDim.x + threadIdx.x;
    int total = N * 144;
    if (t >= total) return;
    int n = t / 144;
    int c = t - n * 144;
    float val = 0.0f;
    if (c < 16) {
        const float* xr = nf + n * 16;
        #pragma unroll
        for (int u = 0; u < 16; ++u)
            val = fmaf(xr[u], Wsi[u * 16 + c], val);
        val *= 0.25f;
    }
    out[t] = val;
}

__global__ __launch_bounds__(256)
void edge_kernel_atomic(const float* __restrict__ nf, const int* __restrict__ ei,
                        const float* __restrict__ sh, const float* __restrict__ radial,
                        const float* __restrict__ W1, const float* __restrict__ W2,
                        float* __restrict__ out, int E) {
    int e = blockIdx.x * blockDim.x + threadIdx.x;
    if (e >= E) return;
    int src = ei[e];
    int dst = ei[E + e];
    float r[16], x[16];
    #pragma unroll
    for (int u = 0; u < 16; ++u) r[u] = radial[e * 16 + u] * 0.25f;
    #pragma unroll
    for (int u = 0; u < 16; ++u) x[u] = nf[src * 16 + u] * 0.03125f;
    float acc[48];
    #pragma unroll
    for (int j = 0; j < 48; ++j) acc[j] = 0.0f;
    for (int k = 0; k < 64; ++k) {
        float z = 0.0f;
        #pragma unroll
        for (int u = 0; u < 16; ++u) z = fmaf(r[u], W1[u * 64 + k], z);
        float hk = z / (1.0f + __expf(-z));
        const float* w2k = W2 + k * 768;
        #pragma unroll 4
        for (int u = 0; u < 16; ++u) {
            float p = hk * x[u];
            const float* w = w2k + u * 16;
            #pragma unroll
            for (int l = 0; l < 3; ++l)
                #pragma unroll
                for (int v = 0; v < 16; ++v)
                    acc[l * 16 + v] = fmaf(p, w[l * 256 + v], acc[l * 16 + v]);
        }
    }
    const float* she = sh + e * 9;
    float* orow = out + (long)dst * 144;
    #pragma unroll
    for (int v = 0; v < 16; ++v) atomicAdd(&orow[v], acc[v] * she[0]);
    #pragma unroll
    for (int v = 0; v < 16; ++v)
        for (int m = 0; m < 3; ++m)
            atomicAdd(&orow[16 + v * 3 + m], acc[16 + v] * she[1 + m]);
    #pragma unroll
    for (int v = 0; v < 16; ++v)
        for (int m = 0; m < 5; ++m)
            atomicAdd(&orow[64 + v * 5 + m], acc[32 + v] * she[4 + m]);
}

// ---------------------------------------------------------------------------

extern "C" void kernel_launch(void* const* d_in, const int* in_sizes, int n_in,
                              void* d_out, int out_size, void* d_ws, size_t ws_size,
                              hipStream_t stream) {
    const float* nf     = (const float*)d_in[0];
    const int*   ei     = (const int*)  d_in[1];
    const float* sh     = (const float*)d_in[2];
    const float* radial = (const float*)d_in[3];
    const float* W1     = (const float*)d_in[4];
    const float* W2     = (const float*)d_in[5];
    const float* Wsi    = (const float*)d_in[6];
    float* out = (float*)d_out;

    const int N = in_sizes[0] / 16;
    const int E = in_sizes[1] / 2;

    size_t mix_bytes  = (size_t)E * 64 * sizeof(_Float16);   // 128-B padded f16 rows
    size_t offs_bytes = (size_t)(N + 1) * sizeof(int);
    size_t curs_bytes = (size_t)N * sizeof(int);
    size_t pos_bytes  = (size_t)E * sizeof(int);
    size_t shs_bytes  = (size_t)E * 9 * sizeof(float);
    size_t bfrag_off  = (mix_bytes + offs_bytes + curs_bytes + pos_bytes + shs_bytes + 127) & ~(size_t)127;
    size_t bfrag_bytes = 96 * 512 * sizeof(_Float16);        // 96 KB
    size_t need = bfrag_off + bfrag_bytes;

    if (ws_size < need) {
        int total = N * 144;
        hipLaunchKernelGGL(si_init_kernel, dim3((total + 255) / 256), dim3(256), 0, stream,
                           nf, Wsi, out, N);
        hipLaunchKernelGGL(edge_kernel_atomic, dim3((E + 255) / 256), dim3(256), 0, stream,
                           nf, ei, sh, radial, W1, W2, out, E);
        return;
    }

    char* wsb = (char*)d_ws;
    _Float16* mixs = (_Float16*)wsb;
    int*   offs = (int*)(wsb + mix_bytes);
    int*   curs = (int*)(wsb + mix_bytes + offs_bytes);
    int*   pos  = (int*)(wsb + mix_bytes + offs_bytes + curs_bytes);
    float* shs  = (float*)(wsb + mix_bytes + offs_bytes + curs_bytes + pos_bytes);
    _Float16* bfrag = (_Float16*)(wsb + bfrag_off);

    (void)hipMemsetAsync(offs, 0, offs_bytes + curs_bytes, stream);

    int eb = (E + 255) / 256;
    hipLaunchKernelGGL(bfrag_prep_kernel, dim3(192), dim3(256), 0, stream, W2, bfrag);
    hipLaunchKernelGGL(hist_kernel, dim3(eb), dim3(256), 0, stream, ei, offs, E);
    hipLaunchKernelGGL(scan_kernel, dim3(1), dim3(1024), 0, stream, offs, N + 1);
    hipLaunchKernelGGL(scatter_kernel, dim3(eb), dim3(256), 0, stream,
                       ei, sh, offs, curs, pos, shs, E);

    int mblocks = (E + 255) / 256;
    hipLaunchKernelGGL(edge_mfma_kernel, dim3(mblocks), dim3(256), 0, stream,
                       nf, ei, radial, W1, bfrag, pos, mixs, E);
    hipLaunchKernelGGL(gather_kernel, dim3((N + 3) / 4), dim3(256), 0, stream,
                       mixs, shs, offs, nf, Wsi, out, N);
}